// Round 14
// baseline (193.100 us; speedup 1.0000x reference)
//
#include <hip/hip_runtime.h>
#include <math.h>

#define S_TOT   2048
#define NNODES  128
#define D_DIM   127
#define N_STEPS 126

typedef unsigned short ushort_t;
typedef unsigned int   uint_t;
typedef __attribute__((ext_vector_type(8))) short bfrag;   // 8 bf16 = 4 VGPR
typedef __attribute__((ext_vector_type(4))) float f4;

__device__ __forceinline__ float softplus_f(float x) {
    return log1pf(expf(-fabsf(x))) + fmaxf(x, 0.0f);
}
__device__ __forceinline__ float normal_cdf_f(float x) {
    return 0.5f * (1.0f + erff(x * 0.7071067811865475f));
}
__device__ __forceinline__ float frl(float x, int lane) {
    return __int_as_float(__builtin_amdgcn_readlane(__float_as_int(x), lane));
}
// 64-lane sum via DPP; returns wave-uniform total. (used by ll_kernel)
__device__ __forceinline__ float wave_sum(float x) {
    float r = x; int v;
    v = __builtin_amdgcn_update_dpp(0, __float_as_int(r), 0x111, 0xf, 0xf, true); r += __int_as_float(v);
    v = __builtin_amdgcn_update_dpp(0, __float_as_int(r), 0x112, 0xf, 0xf, true); r += __int_as_float(v);
    v = __builtin_amdgcn_update_dpp(0, __float_as_int(r), 0x114, 0xf, 0xf, true); r += __int_as_float(v);
    v = __builtin_amdgcn_update_dpp(0, __float_as_int(r), 0x118, 0xf, 0xf, true); r += __int_as_float(v);
    v = __builtin_amdgcn_update_dpp(0, __float_as_int(r), 0x142, 0xa, 0xf, true); r += __int_as_float(v);
    v = __builtin_amdgcn_update_dpp(0, __float_as_int(r), 0x143, 0xc, 0xf, true); r += __int_as_float(v);
    return frl(r, 63);
}
__device__ __forceinline__ ushort_t f2bf(float x) {        // RNE fp32 -> bf16
    uint_t u = __float_as_uint(x);
    uint_t r = u + 0x7fffu + ((u >> 16) & 1u);
    return (ushort_t)(r >> 16);
}
__device__ __forceinline__ float bf2f(ushort_t h) {
    return __uint_as_float(((uint_t)h) << 16);
}
__device__ __forceinline__ ushort_t f2h(float x) {
    return __builtin_bit_cast(ushort_t, (_Float16)x);
}
__device__ __forceinline__ float h2f(ushort_t h) {
    return (float)__builtin_bit_cast(_Float16, h);
}

// ---------------------------------------------------------------------------
// Kernel 0: symmetrized counts packed as bf16 pair: lo = csym, hi = asym-csym
// ---------------------------------------------------------------------------
__global__ __launch_bounds__(256) void prep_counts(
        const int* __restrict__ all_t, const int* __restrict__ cor_t,
        uint_t* __restrict__ pk) {
    int i = blockIdx.x * 256 + threadIdx.x;       // 16384
    int n = i >> 7, m = i & 127;
    int at = all_t[i], ct = cor_t[i];
    if (n != m) { at += all_t[m * 128 + n]; ct += cor_t[m * 128 + n]; }
    pk[i] = (uint_t)f2bf((float)ct) | ((uint_t)f2bf((float)(at - ct)) << 16);
}

// ---------------------------------------------------------------------------
// Shared MFMA helpers (swizzled [128 rows][128 cols] bf16 LDS tiles)
// ---------------------------------------------------------------------------
__device__ __forceinline__ bfrag ldfrag(const ushort_t* base, int row, int kelem) {
    int byte = ((row << 8) + (kelem << 1)) ^ ((row & 7) << 4);
    return *(const bfrag*)((const char*)base + byte);
}

// ---------------------------------------------------------------------------
// Kernel 1: per-sample Gram G = A A^T (upper triangle), hi/lo bf16 3-MFMA,
// stored fp16 [sample][126 rows][128 cols]. G transpose ambiguity is harmless
// (symmetric). 256 threads; wave w owns tile-rows {w, 7-w} (9 tiles).
// ---------------------------------------------------------------------------
template<int W>
__device__ __forceinline__ void gram3_w(const ushort_t* Hs, const ushort_t* Ls,
                                        f4 (&acc)[9], int lr, int lg) {
    constexpr int RA = W, RB = 7 - W;
    #pragma unroll
    for (int ks = 0; ks < 4; ++ks) {
        const int kb = ks * 32 + lg * 8;
        const bfrag ha = ldfrag(Hs, RA * 16 + lr, kb), la = ldfrag(Ls, RA * 16 + lr, kb);
        const bfrag hb = ldfrag(Hs, RB * 16 + lr, kb), lb = ldfrag(Ls, RB * 16 + lr, kb);
        #pragma unroll
        for (int TC = W; TC < 8; ++TC) {
            const bfrag ch = ldfrag(Hs, TC * 16 + lr, kb), cl = ldfrag(Ls, TC * 16 + lr, kb);
            f4& A = acc[TC - W];
            A = __builtin_amdgcn_mfma_f32_16x16x32_bf16(ha, ch, A, 0, 0, 0);
            A = __builtin_amdgcn_mfma_f32_16x16x32_bf16(ha, cl, A, 0, 0, 0);
            A = __builtin_amdgcn_mfma_f32_16x16x32_bf16(la, ch, A, 0, 0, 0);
            if (TC >= RB) {
                f4& B = acc[TC + 1];
                B = __builtin_amdgcn_mfma_f32_16x16x32_bf16(hb, ch, B, 0, 0, 0);
                B = __builtin_amdgcn_mfma_f32_16x16x32_bf16(hb, cl, B, 0, 0, 0);
                B = __builtin_amdgcn_mfma_f32_16x16x32_bf16(lb, ch, B, 0, 0, 0);
            }
        }
    }
}

template<int W>
__device__ __forceinline__ void store_g(const f4 (&acc)[9], ushort_t* g,
                                        int lr, int lg) {
    constexpr int RA = W, RB = 7 - W;
    #pragma unroll
    for (int TC = W; TC < 8; ++TC) {
        #pragma unroll
        for (int q = 0; q < 4; ++q) {
            const int m = TC * 16 + lr;
            const int nA = RA * 16 + 4 * lg + q;          // <= 63: in range
            g[nA * 128 + m] = f2h(acc[TC - W][q]);
            if (TC >= RB) {
                const int nB = RB * 16 + 4 * lg + q;      // up to 127
                if (nB < 126) g[nB * 128 + m] = f2h(acc[TC + 1][q]);
            }
        }
    }
}

__global__ __launch_bounds__(256) void gram_kernel(
        const float* __restrict__ a_raw, ushort_t* __restrict__ G16, int s_base) {
    const int li = blockIdx.x;
    const int s  = s_base + li;
    const int t  = threadIdx.x;

    __shared__ __align__(16) ushort_t Hs[128 * 128];   // 32 KB
    __shared__ __align__(16) ushort_t Ls[128 * 128];   // 32 KB

    // zero both planes (covers row/col padding)
    {
        uint4* hz = (uint4*)Hs; uint4* lz = (uint4*)Ls;
        const uint4 z = make_uint4(0u, 0u, 0u, 0u);
        for (int i = t; i < 2048; i += 256) { hz[i] = z; lz[i] = z; }
    }
    __syncthreads();

    // stage A (16002 floats) -> hi/lo bf16, swizzled. magic div by 127.
    const float* ap = a_raw + (size_t)s * 16002;
    for (int c = t; c < 4001; c += 256) {
        const int f0 = 4 * c;
        float2 qa, qb;
        qa = *(const float2*)(ap + f0);
        if (c < 4000) qb = *(const float2*)(ap + f0 + 2);
        else          qb = make_float2(0.0f, 0.0f);
        #pragma unroll
        for (int e = 0; e < 4; ++e) {
            const int f = f0 + e;
            if (f < 16002) {
                const int row = (int)(((unsigned)f * 33027u) >> 22);
                const int col = f - row * 127;
                const float val = (e == 0) ? qa.x : (e == 1) ? qa.y
                                : (e == 2) ? qb.x : qb.y;
                const ushort_t h  = f2bf(val);
                const ushort_t lo = f2bf(val - bf2f(h));
                const int off = ((row << 8) + (col << 1)) ^ ((row & 7) << 4);
                *(ushort_t*)((char*)Hs + off) = h;
                *(ushort_t*)((char*)Ls + off) = lo;
            }
        }
    }
    __syncthreads();

    const int l = t & 63, w = t >> 6, lr = l & 15, lg = l >> 4;
    f4 acc[9];
    #pragma unroll
    for (int i = 0; i < 9; ++i) acc[i] = (f4)(0.0f);

    ushort_t* g = G16 + (size_t)li * 16384;
    switch (w) {
        case 0: gram3_w<0>(Hs, Ls, acc, lr, lg); store_g<0>(acc, g, lr, lg); break;
        case 1: gram3_w<1>(Hs, Ls, acc, lr, lg); store_g<1>(acc, g, lr, lg); break;
        case 2: gram3_w<2>(Hs, Ls, acc, lr, lg); store_g<2>(acc, g, lr, lg); break;
        default: gram3_w<3>(Hs, Ls, acc, lr, lg); store_g<3>(acc, g, lr, lg); break;
    }
}

// ---------------------------------------------------------------------------
// Kernel 2: scalar recurrence + emission. One wave per sample.
// Phase 1: 126 steps; va via ONE dynamic readlane of lane-distributed Y
//   (Y_k = v.a_k, updated Y = alpha*Y + beta*G[j][k] elementwise); scalar
//   tail identical to verified R13 code; alpha/beta -> LDS table.
// Phase 2: x emission with R13's verified A-ring/xstage machinery, v update
//   v = alpha*v + beta*a (no cross-lane ops at all).
// ---------------------------------------------------------------------------
#define LDR1(A, B, row)                                                       \
    { const float* _p = ap + (size_t)(row) * D_DIM + 2 * lane;                \
      A = _p[0];                                                              \
      float _t = _p[d1ok ? 1 : 0];                                            \
      B = d1ok ? _t : 0.0f; }

#define LOAD_G(BASE, GUARD)                                                   \
    { const int _b = (BASE); const bool _gd = (GUARD);                        \
      if (!_gd || _b + 0  < 126) LDR1(sa0,  sb0,  _b + 0)  else { sa0 = 0; sb0 = 0; }   \
      if (!_gd || _b + 1  < 126) LDR1(sa1,  sb1,  _b + 1)  else { sa1 = 0; sb1 = 0; }   \
      if (!_gd || _b + 2  < 126) LDR1(sa2,  sb2,  _b + 2)  else { sa2 = 0; sb2 = 0; }   \
      if (!_gd || _b + 3  < 126) LDR1(sa3,  sb3,  _b + 3)  else { sa3 = 0; sb3 = 0; }   \
      if (!_gd || _b + 4  < 126) LDR1(sa4,  sb4,  _b + 4)  else { sa4 = 0; sb4 = 0; }   \
      if (!_gd || _b + 5  < 126) LDR1(sa5,  sb5,  _b + 5)  else { sa5 = 0; sb5 = 0; }   \
      if (!_gd || _b + 6  < 126) LDR1(sa6,  sb6,  _b + 6)  else { sa6 = 0; sb6 = 0; }   \
      if (!_gd || _b + 7  < 126) LDR1(sa7,  sb7,  _b + 7)  else { sa7 = 0; sb7 = 0; }   \
      if (!_gd || _b + 8  < 126) LDR1(sa8,  sb8,  _b + 8)  else { sa8 = 0; sb8 = 0; }   \
      if (!_gd || _b + 9  < 126) LDR1(sa9,  sb9,  _b + 9)  else { sa9 = 0; sb9 = 0; }   \
      if (!_gd || _b + 10 < 126) LDR1(sa10, sb10, _b + 10) else { sa10 = 0; sb10 = 0; } \
      if (!_gd || _b + 11 < 126) LDR1(sa11, sb11, _b + 11) else { sa11 = 0; sb11 = 0; } \
      if (!_gd || _b + 12 < 126) LDR1(sa12, sb12, _b + 12) else { sa12 = 0; sb12 = 0; } \
      if (!_gd || _b + 13 < 126) LDR1(sa13, sb13, _b + 13) else { sa13 = 0; sb13 = 0; } \
      if (!_gd || _b + 14 < 126) LDR1(sa14, sb14, _b + 14) else { sa14 = 0; sb14 = 0; } \
      if (!_gd || _b + 15 < 126) LDR1(sa15, sb15, _b + 15) else { sa15 = 0; sb15 = 0; } }

#define WRITE_G(SB)                                                           \
    { const int _s = (SB);                                                    \
      *(float2*)&abuf[_s + 0 ][2 * lane] = make_float2(sa0,  sb0);            \
      *(float2*)&abuf[_s + 1 ][2 * lane] = make_float2(sa1,  sb1);            \
      *(float2*)&abuf[_s + 2 ][2 * lane] = make_float2(sa2,  sb2);            \
      *(float2*)&abuf[_s + 3 ][2 * lane] = make_float2(sa3,  sb3);            \
      *(float2*)&abuf[_s + 4 ][2 * lane] = make_float2(sa4,  sb4);            \
      *(float2*)&abuf[_s + 5 ][2 * lane] = make_float2(sa5,  sb5);            \
      *(float2*)&abuf[_s + 6 ][2 * lane] = make_float2(sa6,  sb6);            \
      *(float2*)&abuf[_s + 7 ][2 * lane] = make_float2(sa7,  sb7);            \
      *(float2*)&abuf[_s + 8 ][2 * lane] = make_float2(sa8,  sb8);            \
      *(float2*)&abuf[_s + 9 ][2 * lane] = make_float2(sa9,  sb9);            \
      *(float2*)&abuf[_s + 10][2 * lane] = make_float2(sa10, sb10);           \
      *(float2*)&abuf[_s + 11][2 * lane] = make_float2(sa11, sb11);           \
      *(float2*)&abuf[_s + 12][2 * lane] = make_float2(sa12, sb12);           \
      *(float2*)&abuf[_s + 13][2 * lane] = make_float2(sa13, sb13);           \
      *(float2*)&abuf[_s + 14][2 * lane] = make_float2(sa14, sb14);           \
      *(float2*)&abuf[_s + 15][2 * lane] = make_float2(sa15, sb15); }

// Phase-1 step: SC = ring slot of G row j; SR = slot to refill (row j+3)
#define PSTEP(JV, SC, SR)                                                     \
    {                                                                         \
        const int j = (JV);                                                   \
        const float ysel = (j & 1) ? Y1 : Y0;                                 \
        const float va = __int_as_float(                                      \
            __builtin_amdgcn_readlane(__float_as_int(ysel), j >> 1));         \
        float ua = fmaf(fmaf(-vp0, aE0U, va), rcp_v, aE0U);                   \
        float w1 = fmaf(-ua, vp1s, aE1U);                                     \
        float inv = __builtin_amdgcn_rsqf(fmaf(-va, va, aaU));                \
        float invs = (w1 >= 0.0f) ? -inv : inv;                               \
        float sf = sU * invs;                                                 \
        float alpha = fmaf(-sf, va, cU);                                      \
        if (lane == 0) ab_t[j] = make_float2(alpha, sf);                      \
        float np0 = fmaf(cU, vp0, sf * fmaf(-va, vp0, aE0U));                 \
        float np1 = fmaf(cU, vp1, sf * fmaf(-va, vp1, aE1U));                 \
        vp0 = np0; vp1 = np1;                                                 \
        { float ns = copysignf(1.0f, vp0);                                    \
          rcp_v = __builtin_amdgcn_rcpf(vp0 + ns); vp1s = vp1 * ns; }         \
        { const uint_t gw = gR[SC];                                           \
          const float g0 = h2f((ushort_t)(gw & 0xffffu));                     \
          const float g1 = h2f((ushort_t)(gw >> 16));                         \
          Y0 = fmaf(alpha, Y0, sf * g0);                                      \
          Y1 = fmaf(alpha, Y1, sf * g1); }                                    \
        aaU = aa1; aE0U = aE0_1; aE1U = aE1_1; cU = c1; sU = s1;              \
        aa1 = gdiag[j + 2];                                                   \
        { float2 e = aEl[j + 2]; aE0_1 = e.x; aE1_1 = e.y; }                  \
        { float2 cc = cls2[j + 2]; c1 = cc.x; s1 = cc.y; }                    \
        { const int pr = (j + 3 < 126) ? (j + 3) : 125;                       \
          gR[SR] = gp[pr * 64 + lane]; }                                      \
    }

// Phase-2 step (R13 STEP_CORE minus all cross-lane work)
#define ESTEP(I, SC, SR, ROWRD, ABI, DLSI, FLUSH)                             \
    {                                                                         \
        const float ca = ra_r[SC], cb = rb_r[SC];                             \
        v0 = fmaf(aU, v0, bU * ca);                                           \
        v1 = fmaf(aU, v1, bU * cb);                                           \
        x0 = fmaf(dU, v0, x0); x1 = fmaf(dU, v1, x1);                         \
        { uint_t pk;                                                          \
          asm("v_cvt_pk_bf16_f32 %0, %1, %2" : "=v"(pk) : "v"(x0), "v"(x1));  \
          xstage[(((I) + 2) & 7) * 64 + lane] = pk; }                         \
        aU = a1n; bU = b1n; dU = d1;                                          \
        { float2 abv = ab_t[ABI]; a1n = abv.x; b1n = abv.y; }                 \
        d1 = dls[DLSI];                                                       \
        { float2 nx = *(float2*)&abuf[ROWRD][2 * lane];                       \
          ra_r[SR] = nx.x; rb_r[SR] = nx.y; }                                 \
        if (FLUSH) {                                                          \
            uint4 t0v = *(uint4*)&xstage[4 * lane];                           \
            uint4 t1v = *(uint4*)&xstage[256 + 4 * lane];                     \
            uint_t* dst = xg + ((I) - 5) * 64;                                \
            *(uint4*)(dst + 4 * lane) = t0v;                                  \
            *(uint4*)(dst + 256 + 4 * lane) = t1v;                            \
        }                                                                     \
    }

#define RR(v) ((((v) < 125) ? (v) : 125) & 31)     // clamped refill row

__global__
__attribute__((amdgpu_flat_work_group_size(64, 64), amdgpu_waves_per_eu(2, 2)))
void scal_kernel(
        const float* __restrict__ d_raw, const float* __restrict__ c_raw,
        const float* __restrict__ a_raw, const ushort_t* __restrict__ G16,
        uint_t* __restrict__ xout, int s_base) {
    const int li = blockIdx.x;
    const int s  = s_base + li;
    const int lane = threadIdx.x;
    const bool d1ok = lane < 63;

    __shared__ __align__(16) float abuf[32][128];  // 16 KB emission A-ring
    __shared__ __align__(16) uint_t xstage[512];   // 2 KB
    __shared__ float  dls[128];
    __shared__ float2 cls2[128];
    __shared__ float2 ab_t[128];                   // alpha/beta table
    __shared__ float2 aEl[128];                    // a[j][0], a[j][1]
    __shared__ float  gdiag[128];                  // G[j][j]

    // ---- tables ----
    float t0 = softplus_f(d_raw[(size_t)s * D_DIM + lane]);
    dls[lane] = t0;
    dls[64 + lane] = d1ok ? softplus_f(d_raw[(size_t)s * D_DIM + 64 + lane]) : 0.0f;
    {
        float cv = c_raw[(size_t)s * N_STEPS + lane];
        cls2[lane] = make_float2(__cosf(cv), __sinf(cv));
        if (lane < 62) {
            float cv2 = c_raw[(size_t)s * N_STEPS + 64 + lane];
            cls2[64 + lane] = make_float2(__cosf(cv2), __sinf(cv2));
        } else {
            cls2[64 + lane] = make_float2(0.0f, 0.0f);
        }
    }
    const float* ap = a_raw + (size_t)s * N_STEPS * D_DIM;
    {   // aE columns (rows lane, lane+64)
        const float* r0 = ap + (size_t)lane * D_DIM;
        aEl[lane] = make_float2(r0[0], r0[1]);
        if (lane < 62) {
            const float* r1 = ap + (size_t)(64 + lane) * D_DIM;
            aEl[64 + lane] = make_float2(r1[0], r1[1]);
        } else {
            aEl[64 + lane] = make_float2(0.0f, 0.0f);
        }
    }
    const ushort_t* gbase = G16 + (size_t)li * 16384;
    gdiag[lane] = h2f(gbase[lane * 129]);
    gdiag[64 + lane] = (lane < 62) ? h2f(gbase[(size_t)(64 + lane) * 129]) : 0.0f;
    if (lane < 2) ab_t[126 + lane] = make_float2(0.0f, 0.0f);

    // ---- issue emission-phase A prefetch early (held in regs thru phase 1)
    float sa0, sa1, sa2, sa3, sa4, sa5, sa6, sa7,
          sa8, sa9, sa10, sa11, sa12, sa13, sa14, sa15;
    float sb0, sb1, sb2, sb3, sb4, sb5, sb6, sb7,
          sb8, sb9, sb10, sb11, sb12, sb13, sb14, sb15;
    LOAD_G(0, false)  WRITE_G(0)
    LOAD_G(16, false) WRITE_G(16)
    LOAD_G(32, false)                               // held, written at g=0

    // ---- phase 1: scalar recurrence ----
    const uint_t* gp = (const uint_t*)gbase;        // G row j: gp[j*64 + lane]
    uint_t gR[4];
    gR[0] = gp[0 * 64 + lane];
    gR[1] = gp[1 * 64 + lane];
    gR[2] = gp[2 * 64 + lane];
    gR[3] = 0u;

    float Y0 = aEl[2 * lane].x;
    float Y1 = aEl[2 * lane + 1].x;
    float vp0 = 1.0f, vp1 = 0.0f, vp1s = 0.0f, rcp_v = 0.5f;
    float cU, sU, c1, s1;
    { float2 cc = cls2[0]; cU = cc.x; sU = cc.y; }
    { float2 cc = cls2[1]; c1 = cc.x; s1 = cc.y; }
    float aaU = gdiag[0], aa1 = gdiag[1];
    float aE0U, aE1U, aE0_1, aE1_1;
    { float2 e = aEl[0]; aE0U = e.x; aE1U = e.y; }
    { float2 e = aEl[1]; aE0_1 = e.x; aE1_1 = e.y; }

    #pragma unroll 1
    for (int q2 = 0; q2 < 31; ++q2) {
        const int jb = q2 << 2;
        PSTEP(jb + 0, 0, 3)
        PSTEP(jb + 1, 1, 0)
        PSTEP(jb + 2, 2, 1)
        PSTEP(jb + 3, 3, 2)
    }
    PSTEP(124, 0, 3)
    PSTEP(125, 1, 0)

    // ---- phase 2: emission ----
    uint_t* xg = xout + (size_t)li * NNODES * 64;

    float ra_r[4], rb_r[4];
    { float2 tv = *(float2*)&abuf[0][2 * lane]; ra_r[0] = tv.x; rb_r[0] = tv.y; }
    { float2 tv = *(float2*)&abuf[1][2 * lane]; ra_r[1] = tv.x; rb_r[1] = tv.y; }
    { float2 tv = *(float2*)&abuf[2][2 * lane]; ra_r[2] = tv.x; rb_r[2] = tv.y; }
    ra_r[3] = 0.0f; rb_r[3] = 0.0f;

    float aU, bU, a1n, b1n;
    { float2 abv = ab_t[0]; aU = abv.x; bU = abv.y; }
    { float2 abv = ab_t[1]; a1n = abv.x; b1n = abv.y; }
    float dU = dls[1], d1 = dls[2];

    float v0 = (lane == 0) ? 1.0f : 0.0f, v1 = 0.0f;
    float x0 = (lane == 0) ? t0 : 0.0f, x1 = 0.0f;

    xstage[lane] = 0u;                              // x row 0
    {
        uint_t pk0;
        asm("v_cvt_pk_bf16_f32 %0, %1, %2" : "=v"(pk0) : "v"(x0), "v"(x1));
        xstage[64 + lane] = pk0;                    // x row 1
    }

    #pragma unroll 1
    for (int q = 0; q < 31; ++q) {
        const int i0 = q << 2;
        const bool fl = (q & 1) != 0;
        ESTEP(i0 + 0, 0, 3, RR(i0 + 3), i0 + 2, i0 + 3, false)
        ESTEP(i0 + 1, 1, 0, RR(i0 + 4), i0 + 3, i0 + 4, fl)
        ESTEP(i0 + 2, 2, 1, RR(i0 + 5), i0 + 4, i0 + 5, false)
        ESTEP(i0 + 3, 3, 2, RR(i0 + 6), i0 + 5, i0 + 6, false)
        if ((q & 3) == 3) {
            const int g = q >> 2;                   // 0..6
            if (g <= 5) { WRITE_G((g & 1) << 4) }
            if (g <= 4) LOAD_G((g + 3) << 4, g == 4)
        }
    }
    ESTEP(124, 0, 3, 125 & 31, 126, 127, false)
    ESTEP(125, 1, 0, 125 & 31, 127, 127, true)
}
#undef PSTEP
#undef ESTEP
#undef RR
#undef LOAD_G
#undef WRITE_G
#undef LDR1

// ---------------------------------------------------------------------------
// Kernel 3: MFMA gram (single 32KB bf16 LDS stage) + B-S tail log-lik.
// ---------------------------------------------------------------------------
template<int W>
__device__ __forceinline__ void gram_w(const ushort_t* Xs, f4 (&acc)[9],
                                       int lr, int lg) {
    constexpr int RA = W, RB = 7 - W;
    #pragma unroll
    for (int ks = 0; ks < 4; ++ks) {
        const int kb = ks * 32 + lg * 8;
        const bfrag ha = ldfrag(Xs, RA * 16 + lr, kb);
        const bfrag hb = ldfrag(Xs, RB * 16 + lr, kb);
        #pragma unroll
        for (int TC = W; TC < 8; ++TC) {
            const bfrag bh = ldfrag(Xs, TC * 16 + lr, kb);
            acc[TC - W] = __builtin_amdgcn_mfma_f32_16x16x32_bf16(ha, bh, acc[TC - W], 0, 0, 0);
            if (TC >= RB)
                acc[TC + 1] = __builtin_amdgcn_mfma_f32_16x16x32_bf16(hb, bh, acc[TC + 1], 0, 0, 0);
        }
    }
}

template<int W>
__device__ __forceinline__ void write_sq(const f4 (&acc)[9], float* sq, int lr, int lg) {
    #pragma unroll
    for (int q = 0; q < 4; ++q) {
        if (4 * lg + q == lr) {
            sq[W * 16 + lr]       = acc[0][q];
            sq[(7 - W) * 16 + lr] = acc[8 - W][q];
        }
    }
}

__device__ __forceinline__ float entry_ll(float g, float sqn, float sqm,
        uint_t cw, float lam, float one_m2l) {
    const float d2 = fmaxf(sqn + sqm - 2.0f * g, 0.0f);
    const float pd = __builtin_amdgcn_sqrtf(d2);
    const float A = 0.344f, B = 5.334f, IA = 0.656f, C = 0.3989422804f;
    const float z1 = 0.70710678f * pd, z2 = 0.5f * pd;
    const float e1 = __expf(-0.25f  * d2) * C;
    const float e2 = __expf(-0.125f * d2) * C;
    const float den1 = fmaf(A, __builtin_amdgcn_sqrtf(fmaf(0.5f,  d2, B)), IA * z1);
    const float den2 = fmaf(A, __builtin_amdgcn_sqrtf(fmaf(0.25f, d2, B)), IA * z2);
    const float F1 = e1 * __builtin_amdgcn_rcpf(den1);
    const float F2 = e2 * __builtin_amdgcn_rcpf(den2);
    const float qax = F1 + F2 - 2.0f * F1 * F2;
    float qp = fmaf(one_m2l, qax, lam);
    qp = fminf(fmaxf(qp, 1e-7f), 1.0f - 1e-7f);
    const float pp = 1.0f - qp;
    const float c   = bf2f((ushort_t)(cw & 0xffffu));
    const float amc = bf2f((ushort_t)(cw >> 16));
    return c * __logf(pp) + amc * __logf(qp);
}

__device__ __forceinline__ float tile_ll(f4 a, int TR, int TC, bool diag,
        int lr, int lg, const float* sq, const uint_t* __restrict__ cnt,
        float lam, float one_m2l) {
    float s = 0.0f;
    #pragma unroll
    for (int q = 0; q < 4; ++q) {
        const int n = TR * 16 + 4 * lg + q;
        const int m = TC * 16 + lr;
        if (!diag || (4 * lg + q) <= lr)
            s += entry_ll(a[q], sq[n], sq[m], cnt[n * 128 + m], lam, one_m2l);
    }
    return s;
}

template<int W>
__device__ __forceinline__ float epi(const f4 (&acc)[9], const float* sq,
        const uint_t* __restrict__ cnt, int lr, int lg, float lam, float one_m2l) {
    constexpr int RA = W, RB = 7 - W;
    float s = 0.0f;
    #pragma unroll
    for (int TC = W; TC < 8; ++TC) {
        s += tile_ll(acc[TC - W], RA, TC, (TC == RA), lr, lg, sq, cnt, lam, one_m2l);
        if (TC >= RB)
            s += tile_ll(acc[TC + 1], RB, TC, (TC == RB), lr, lg, sq, cnt, lam, one_m2l);
    }
    return s;
}

__global__ __launch_bounds__(256, 4) void ll_kernel(
        const uint_t* __restrict__ x_g,
        const float* __restrict__ l_raw, const uint_t* __restrict__ cnt,
        float* __restrict__ sums, int s_base) {
    const int li = blockIdx.x;
    const int s  = s_base + li;
    const int t  = threadIdx.x;

    __shared__ __align__(16) ushort_t Xs[NNODES * 128];   // 32 KB
    __shared__ float sq[NNODES];
    __shared__ float wsum[4];

    const uint_t* gx = x_g + (size_t)li * NNODES * 64;
    const int l = t & 63, w = t >> 6, lr = l & 15, lg = l >> 4;

    #pragma unroll
    for (int ii = 0; ii < 8; ++ii) {
        const int i = t + ii * 256;
        const int row = i >> 4, j = i & 15;
        const uint4 v = *(const uint4*)(gx + row * 64 + j * 4);
        const int b = ((row << 8) + (j << 4)) ^ ((row & 7) << 4);
        *(uint4*)((char*)Xs + b) = v;
    }
    __syncthreads();

    f4 acc[9];
    #pragma unroll
    for (int i = 0; i < 9; ++i) acc[i] = (f4)(0.0f);

    switch (w) {
        case 0: gram_w<0>(Xs, acc, lr, lg); write_sq<0>(acc, sq, lr, lg); break;
        case 1: gram_w<1>(Xs, acc, lr, lg); write_sq<1>(acc, sq, lr, lg); break;
        case 2: gram_w<2>(Xs, acc, lr, lg); write_sq<2>(acc, sq, lr, lg); break;
        default: gram_w<3>(Xs, acc, lr, lg); write_sq<3>(acc, sq, lr, lg); break;
    }
    __syncthreads();

    const float lam = 0.06f * normal_cdf_f(l_raw[s]);
    const float one_m2l = 1.0f - 2.0f * lam;
    float ll = 0.0f;
    switch (w) {
        case 0: ll = epi<0>(acc, sq, cnt, lr, lg, lam, one_m2l); break;
        case 1: ll = epi<1>(acc, sq, cnt, lr, lg, lam, one_m2l); break;
        case 2: ll = epi<2>(acc, sq, cnt, lr, lg, lam, one_m2l); break;
        default: ll = epi<3>(acc, sq, cnt, lr, lg, lam, one_m2l); break;
    }

    const float wtot = wave_sum(ll);
    if (l == 0) wsum[w] = wtot;
    __syncthreads();
    if (t == 0) sums[s] = wsum[0] + wsum[1] + wsum[2] + wsum[3];
}

// ---------------------------------------------------------------------------
// Kernel 4: deterministic mean over S
// ---------------------------------------------------------------------------
__global__ __launch_bounds__(256) void reduce_kernel(
        const float* __restrict__ sums, float* __restrict__ out) {
    __shared__ double sh[256];
    const int t = threadIdx.x;
    double acc = 0.0;
    for (int i = t; i < S_TOT; i += 256) acc += (double)sums[i];
    sh[t] = acc;
    __syncthreads();
    for (int off = 128; off > 0; off >>= 1) {
        if (t < off) sh[t] += sh[t + off];
        __syncthreads();
    }
    if (t == 0) out[0] = (float)(sh[0] / (double)S_TOT);
}

// ---------------------------------------------------------------------------
extern "C" void kernel_launch(void* const* d_in, const int* in_sizes, int n_in,
                              void* d_out, int out_size, void* d_ws, size_t ws_size,
                              hipStream_t stream) {
    (void)in_sizes; (void)n_in; (void)out_size;
    const float* d_raw = (const float*)d_in[0];
    const float* c_raw = (const float*)d_in[1];
    const float* a_raw = (const float*)d_in[2];
    const float* l_raw = (const float*)d_in[3];
    const int*   all_t = (const int*)d_in[4];
    const int*   cor_t = (const int*)d_in[5];
    float* out = (float*)d_out;

    char*   ws   = (char*)d_ws;
    float*  sums = (float*)ws;                        // 8 KB
    uint_t* cnt  = (uint_t*)(ws + 8192);              // 64 KB packed counts
    char*   xbase = ws + 8192 + 65536;
    // per sample: x 32768 B (128 rows x 64 dwords) + G 32768 B (128x128 fp16)
    const size_t per_sample = 65536;

    const size_t head = 8192 + 65536;
    size_t avail = (ws_size > head) ? ws_size - head : 0;
    int chunk = (int)(avail / per_sample);
    if (chunk > S_TOT) chunk = S_TOT;
    if (chunk < 1) chunk = 1;

    prep_counts<<<64, 256, 0, stream>>>(all_t, cor_t, cnt);

    for (int s0 = 0; s0 < S_TOT; s0 += chunk) {
        const int nblk = (S_TOT - s0 < chunk) ? (S_TOT - s0) : chunk;
        uint_t*   xbuf = (uint_t*)xbase;
        ushort_t* G16  = (ushort_t*)(xbase + (size_t)chunk * 32768);
        gram_kernel<<<nblk, 256, 0, stream>>>(a_raw, G16, s0);
        scal_kernel<<<nblk, 64, 0, stream>>>(d_raw, c_raw, a_raw, G16, xbuf, s0);
        ll_kernel<<<nblk, 256, 0, stream>>>(xbuf, l_raw, cnt, sums, s0);
    }
    reduce_kernel<<<1, 256, 0, stream>>>(sums, out);
}

// Round 15
// 100.132 us; speedup vs baseline: 1.9285x; 1.9285x over previous
//
#include <hip/hip_runtime.h>
#include <math.h>

#define S_TOT   2048
#define NNODES  128
#define D_DIM   127
#define N_STEPS 126

typedef unsigned short ushort_t;
typedef unsigned int   uint_t;
typedef __attribute__((ext_vector_type(8))) short bfrag;   // 8 bf16 = 4 VGPR
typedef __attribute__((ext_vector_type(4))) float f4;

__device__ __forceinline__ float softplus_f(float x) {
    return log1pf(expf(-fabsf(x))) + fmaxf(x, 0.0f);
}
__device__ __forceinline__ float normal_cdf_f(float x) {
    return 0.5f * (1.0f + erff(x * 0.7071067811865475f));
}
__device__ __forceinline__ float frl(float x, int lane) {
    return __int_as_float(__builtin_amdgcn_readlane(__float_as_int(x), lane));
}
// 64-lane sum via DPP; returns wave-uniform total.
__device__ __forceinline__ float wave_sum(float x) {
    float r = x; int v;
    v = __builtin_amdgcn_update_dpp(0, __float_as_int(r), 0x111, 0xf, 0xf, true); r += __int_as_float(v);
    v = __builtin_amdgcn_update_dpp(0, __float_as_int(r), 0x112, 0xf, 0xf, true); r += __int_as_float(v);
    v = __builtin_amdgcn_update_dpp(0, __float_as_int(r), 0x114, 0xf, 0xf, true); r += __int_as_float(v);
    v = __builtin_amdgcn_update_dpp(0, __float_as_int(r), 0x118, 0xf, 0xf, true); r += __int_as_float(v);
    v = __builtin_amdgcn_update_dpp(0, __float_as_int(r), 0x142, 0xa, 0xf, true); r += __int_as_float(v);
    v = __builtin_amdgcn_update_dpp(0, __float_as_int(r), 0x143, 0xc, 0xf, true); r += __int_as_float(v);
    return frl(r, 63);
}
__device__ __forceinline__ ushort_t f2bf(float x) {        // RNE fp32 -> bf16
    uint_t u = __float_as_uint(x);
    uint_t r = u + 0x7fffu + ((u >> 16) & 1u);
    return (ushort_t)(r >> 16);
}
__device__ __forceinline__ float bf2f(ushort_t h) {
    return __uint_as_float(((uint_t)h) << 16);
}

// ---------------------------------------------------------------------------
// Kernel 0: symmetrized counts packed as bf16 pair: lo = csym, hi = asym-csym
// ---------------------------------------------------------------------------
__global__ __launch_bounds__(256) void prep_counts(
        const int* __restrict__ all_t, const int* __restrict__ cor_t,
        uint_t* __restrict__ pk) {
    int i = blockIdx.x * 256 + threadIdx.x;       // 16384
    int n = i >> 7, m = i & 127;
    int at = all_t[i], ct = cor_t[i];
    if (n != m) { at += all_t[m * 128 + n]; ct += cor_t[m * 128 + n]; }
    pk[i] = (uint_t)f2bf((float)ct) | ((uint_t)f2bf((float)(at - ct)) << 16);
}

// ---------------------------------------------------------------------------
// Kernel 1: trajectory. Rolled 4-step bodies; ring slots compile-time via
// mod-4 alignment; step index / table indices / flush runtime-uniform.
// (Round-13 verified structure: 100.06 us total, absmax 0.0.)
// ---------------------------------------------------------------------------
#define LDR1(A, B, row)                                                       \
    { const float* _p = ap + (size_t)(row) * D_DIM + 2 * lane;                \
      A = _p[0];                                                              \
      float _t = _p[d1ok ? 1 : 0];   /* lane63 stays in-bounds */             \
      B = d1ok ? _t : 0.0f; }

#define LOAD_G(BASE, GUARD)                                                   \
    { const int _b = (BASE); const bool _gd = (GUARD);                        \
      if (!_gd || _b + 0  < 126) LDR1(sa0,  sb0,  _b + 0)  else { sa0 = 0; sb0 = 0; }   \
      if (!_gd || _b + 1  < 126) LDR1(sa1,  sb1,  _b + 1)  else { sa1 = 0; sb1 = 0; }   \
      if (!_gd || _b + 2  < 126) LDR1(sa2,  sb2,  _b + 2)  else { sa2 = 0; sb2 = 0; }   \
      if (!_gd || _b + 3  < 126) LDR1(sa3,  sb3,  _b + 3)  else { sa3 = 0; sb3 = 0; }   \
      if (!_gd || _b + 4  < 126) LDR1(sa4,  sb4,  _b + 4)  else { sa4 = 0; sb4 = 0; }   \
      if (!_gd || _b + 5  < 126) LDR1(sa5,  sb5,  _b + 5)  else { sa5 = 0; sb5 = 0; }   \
      if (!_gd || _b + 6  < 126) LDR1(sa6,  sb6,  _b + 6)  else { sa6 = 0; sb6 = 0; }   \
      if (!_gd || _b + 7  < 126) LDR1(sa7,  sb7,  _b + 7)  else { sa7 = 0; sb7 = 0; }   \
      if (!_gd || _b + 8  < 126) LDR1(sa8,  sb8,  _b + 8)  else { sa8 = 0; sb8 = 0; }   \
      if (!_gd || _b + 9  < 126) LDR1(sa9,  sb9,  _b + 9)  else { sa9 = 0; sb9 = 0; }   \
      if (!_gd || _b + 10 < 126) LDR1(sa10, sb10, _b + 10) else { sa10 = 0; sb10 = 0; } \
      if (!_gd || _b + 11 < 126) LDR1(sa11, sb11, _b + 11) else { sa11 = 0; sb11 = 0; } \
      if (!_gd || _b + 12 < 126) LDR1(sa12, sb12, _b + 12) else { sa12 = 0; sb12 = 0; } \
      if (!_gd || _b + 13 < 126) LDR1(sa13, sb13, _b + 13) else { sa13 = 0; sb13 = 0; } \
      if (!_gd || _b + 14 < 126) LDR1(sa14, sb14, _b + 14) else { sa14 = 0; sb14 = 0; } \
      if (!_gd || _b + 15 < 126) LDR1(sa15, sb15, _b + 15) else { sa15 = 0; sb15 = 0; } }

#define WRITE_G(SB)                                                           \
    { const int _s = (SB);                                                    \
      *(float2*)&abuf[_s + 0 ][2 * lane] = make_float2(sa0,  sb0);            \
      *(float2*)&abuf[_s + 1 ][2 * lane] = make_float2(sa1,  sb1);            \
      *(float2*)&abuf[_s + 2 ][2 * lane] = make_float2(sa2,  sb2);            \
      *(float2*)&abuf[_s + 3 ][2 * lane] = make_float2(sa3,  sb3);            \
      *(float2*)&abuf[_s + 4 ][2 * lane] = make_float2(sa4,  sb4);            \
      *(float2*)&abuf[_s + 5 ][2 * lane] = make_float2(sa5,  sb5);            \
      *(float2*)&abuf[_s + 6 ][2 * lane] = make_float2(sa6,  sb6);            \
      *(float2*)&abuf[_s + 7 ][2 * lane] = make_float2(sa7,  sb7);            \
      *(float2*)&abuf[_s + 8 ][2 * lane] = make_float2(sa8,  sb8);            \
      *(float2*)&abuf[_s + 9 ][2 * lane] = make_float2(sa9,  sb9);            \
      *(float2*)&abuf[_s + 10][2 * lane] = make_float2(sa10, sb10);           \
      *(float2*)&abuf[_s + 11][2 * lane] = make_float2(sa11, sb11);           \
      *(float2*)&abuf[_s + 12][2 * lane] = make_float2(sa12, sb12);           \
      *(float2*)&abuf[_s + 13][2 * lane] = make_float2(sa13, sb13);           \
      *(float2*)&abuf[_s + 14][2 * lane] = make_float2(sa14, sb14);           \
      *(float2*)&abuf[_s + 15][2 * lane] = make_float2(sa15, sb15); }

// I: step index (runtime, wave-uniform); SC/SA/SR: compile-time ring slots;
// ROWRD: abuf refill row (pre-masked); CLSI/DLSI: lookahead indices;
// FLUSH: runtime-uniform bool; flush writes rows (I-5)..(I+2).
#define STEP_CORE(I, SC, SA, SR, ROWRD, CLSI, DLSI, FLUSH)                    \
    {                                                                         \
        const float ca = ra_r[SC], cb = rb_r[SC];                             \
        float va = wave_sum(fmaf(v0, ca, v1 * cb));                           \
        float ua = fmaf(fmaf(-vp0, aE0U, va), rcp_v, aE0U);                   \
        float w1 = fmaf(-ua, vp1s, aE1U);                                     \
        float inv = __builtin_amdgcn_rsqf(fmaf(-va, va, aaU));                \
        float invs = (w1 >= 0.0f) ? -inv : inv;                               \
        float sf = sU * invs;                                                 \
        float nv0 = fmaf(cU, v0, sf * fmaf(-va, v0, ca));                     \
        float nv1 = fmaf(cU, v1, sf * fmaf(-va, v1, cb));                     \
        float np0 = fmaf(cU, vp0, sf * fmaf(-va, vp0, aE0U));                 \
        float np1 = fmaf(cU, vp1, sf * fmaf(-va, vp1, aE1U));                 \
        v0 = nv0; v1 = nv1; vp0 = np0; vp1 = np1;                             \
        { float ns = copysignf(1.0f, vp0);                                    \
          rcp_v = __builtin_amdgcn_rcpf(vp0 + ns); vp1s = vp1 * ns; }         \
        x0 = fmaf(dU, v0, x0); x1 = fmaf(dU, v1, x1);                         \
        { uint_t pk;                                                          \
          asm("v_cvt_pk_bf16_f32 %0, %1, %2" : "=v"(pk) : "v"(x0), "v"(x1));  \
          xstage[(((I) + 2) & 7) * 64 + lane] = pk; }                         \
        aaU = aa1; aE0U = aE0_1; aE1U = aE1_1; cU = c1; sU = s1; dU = d1;     \
        aa1 = wave_sum(fmaf(ra_r[SA], ra_r[SA], rb_r[SA] * rb_r[SA]));        \
        aE0_1 = frl(ra_r[SA], 0); aE1_1 = frl(rb_r[SA], 0);                   \
        { float2 cs = cls2[CLSI]; c1 = cs.x; s1 = cs.y; }                     \
        d1 = dls[DLSI];                                                       \
        { float2 nx = *(float2*)&abuf[ROWRD][2 * lane];                       \
          ra_r[SR] = nx.x; rb_r[SR] = nx.y; }                                 \
        if (FLUSH) {   /* rows (I-5)..(I+2); slots linear since I%8==5 */     \
            uint4 t0 = *(uint4*)&xstage[4 * lane];                            \
            uint4 t1 = *(uint4*)&xstage[256 + 4 * lane];                      \
            uint_t* dst = xg + ((I) - 5) * 64;                                \
            *(uint4*)(dst + 4 * lane) = t0;                                   \
            *(uint4*)(dst + 256 + 4 * lane) = t1;                             \
        }                                                                     \
    }

#define RR(v) ((((v) < 125) ? (v) : 125) & 31)     // clamped refill row

__global__
__attribute__((amdgpu_flat_work_group_size(64, 64), amdgpu_waves_per_eu(2, 2)))
void traj_kernel(
        const float* __restrict__ d_raw, const float* __restrict__ c_raw,
        const float* __restrict__ a_raw,
        uint_t* __restrict__ xout, int s_base) {
    const int li = blockIdx.x;
    const int s  = s_base + li;
    const int lane = threadIdx.x;
    const bool d1ok = lane < 63;                  // dim 2l+1 <= 126

    __shared__ __align__(16) float abuf[32][128]; // 16 KB (2 groups x 16 rows)
    __shared__ __align__(16) uint_t xstage[512];  // 2 KB (8 x-rows)
    __shared__ float  dls[128];
    __shared__ float2 cls2[128];

    // d (softplus'd), cos/sin tables for uniform broadcast reads (padded 0)
    float t0 = softplus_f(d_raw[(size_t)s * D_DIM + lane]);
    dls[lane] = t0;
    dls[64 + lane] = d1ok ? softplus_f(d_raw[(size_t)s * D_DIM + 64 + lane]) : 0.0f;
    {
        float cv = c_raw[(size_t)s * N_STEPS + lane];
        cls2[lane] = make_float2(__cosf(cv), __sinf(cv));
        if (lane < 62) {
            float cv2 = c_raw[(size_t)s * N_STEPS + 64 + lane];
            cls2[64 + lane] = make_float2(__cosf(cv2), __sinf(cv2));
        } else {
            cls2[64 + lane] = make_float2(0.0f, 0.0f);
        }
    }

    const float* ap = a_raw + (size_t)s * N_STEPS * D_DIM;
    uint_t* xg = xout + (size_t)li * NNODES * 64;

    // staging regs: one 16-row group
    float sa0, sa1, sa2, sa3, sa4, sa5, sa6, sa7,
          sa8, sa9, sa10, sa11, sa12, sa13, sa14, sa15;
    float sb0, sb1, sb2, sb3, sb4, sb5, sb6, sb7,
          sb8, sb9, sb10, sb11, sb12, sb13, sb14, sb15;

    // prologue: G0,G1 staged+written; G2 loaded (written at boundary g=0)
    LOAD_G(0, false)  WRITE_G(0)
    LOAD_G(16, false) WRITE_G(16)
    LOAD_G(32, false)

    // ring (rows i..i+3) + pipelines primed for steps 0,1
    float ra_r[4], rb_r[4];
    { float2 t = *(float2*)&abuf[0][2 * lane]; ra_r[0] = t.x; rb_r[0] = t.y; }
    { float2 t = *(float2*)&abuf[1][2 * lane]; ra_r[1] = t.x; rb_r[1] = t.y; }
    { float2 t = *(float2*)&abuf[2][2 * lane]; ra_r[2] = t.x; rb_r[2] = t.y; }
    ra_r[3] = 0.0f; rb_r[3] = 0.0f;
    float aaU = wave_sum(fmaf(ra_r[0], ra_r[0], rb_r[0] * rb_r[0]));
    float aa1 = wave_sum(fmaf(ra_r[1], ra_r[1], rb_r[1] * rb_r[1]));
    float aE0U = frl(ra_r[0], 0), aE1U = frl(rb_r[0], 0);
    float aE0_1 = frl(ra_r[1], 0), aE1_1 = frl(rb_r[1], 0);
    float cU, sU, c1, s1;
    { float2 cs = cls2[0]; cU = cs.x; sU = cs.y; }
    { float2 cs = cls2[1]; c1 = cs.x; s1 = cs.y; }
    float dU = dls[1], d1 = dls[2];

    // state: v (lane dims), replicated pivots, x
    float v0 = (lane == 0) ? 1.0f : 0.0f, v1 = 0.0f;
    float vp0 = 1.0f, vp1 = 0.0f, vp1s = 0.0f, rcp_v = 0.5f;
    float x0 = (lane == 0) ? t0 : 0.0f, x1 = 0.0f;

    // x rows 0,1 into staging slots 0,1
    xstage[lane] = 0u;
    {
        uint_t pk0;
        asm("v_cvt_pk_bf16_f32 %0, %1, %2" : "=v"(pk0) : "v"(x0), "v"(x1));
        xstage[64 + lane] = pk0;
    }

    // main: ROLLED loop, 31 iterations x 4 steps (i = 0..123).
    #pragma unroll 1
    for (int q = 0; q < 31; ++q) {
        const int i0 = q << 2;
        const bool fl = (q & 1) != 0;
        STEP_CORE(i0 + 0, 0, 2, 3, RR(i0 + 3), i0 + 2, i0 + 3, false)
        STEP_CORE(i0 + 1, 1, 3, 0, RR(i0 + 4), i0 + 3, i0 + 4, fl)
        STEP_CORE(i0 + 2, 2, 0, 1, RR(i0 + 5), i0 + 4, i0 + 5, false)
        STEP_CORE(i0 + 3, 3, 1, 2, RR(i0 + 6), i0 + 5, i0 + 6, false)
        if ((q & 3) == 3) {
            const int g = q >> 2;                 // 0..6
            if (g <= 5) { WRITE_G((g & 1) << 4) } // write G_{g+2}
            if (g <= 4) LOAD_G((g + 3) << 4, g == 4)  // load G_{g+3}
        }
    }
    // final steps 124, 125 (flush at 125 covers rows 120..127)
    STEP_CORE(124, 0, 2, 3, 125 & 31, 126, 127, false)
    STEP_CORE(125, 1, 3, 0, 125 & 31, 127, 127, true)
}
#undef RR
#undef STEP_CORE
#undef LOAD_G
#undef WRITE_G
#undef LDR1

// ---------------------------------------------------------------------------
// Kernel 2: MFMA gram (single 32KB bf16 LDS stage) + B-S tail log-lik.
// 4 waves; wave w owns tile-rows {w, 7-w} via template<int W> (acc = 9 f4).
// ---------------------------------------------------------------------------
__device__ __forceinline__ bfrag ldfrag(const ushort_t* base, int row, int kelem) {
    int byte = ((row << 8) + (kelem << 1)) ^ ((row & 7) << 4);
    return *(const bfrag*)((const char*)base + byte);
}

template<int W>
__device__ __forceinline__ void gram_w(const ushort_t* Xs, f4 (&acc)[9],
                                       int lr, int lg) {
    constexpr int RA = W, RB = 7 - W;
    #pragma unroll
    for (int ks = 0; ks < 4; ++ks) {
        const int kb = ks * 32 + lg * 8;
        const bfrag ha = ldfrag(Xs, RA * 16 + lr, kb);
        const bfrag hb = ldfrag(Xs, RB * 16 + lr, kb);
        #pragma unroll
        for (int TC = W; TC < 8; ++TC) {
            const bfrag bh = ldfrag(Xs, TC * 16 + lr, kb);
            acc[TC - W] = __builtin_amdgcn_mfma_f32_16x16x32_bf16(ha, bh, acc[TC - W], 0, 0, 0);
            if (TC >= RB)
                acc[TC + 1] = __builtin_amdgcn_mfma_f32_16x16x32_bf16(hb, bh, acc[TC + 1], 0, 0, 0);
        }
    }
}

template<int W>
__device__ __forceinline__ void write_sq(const f4 (&acc)[9], float* sq, int lr, int lg) {
    #pragma unroll
    for (int q = 0; q < 4; ++q) {
        if (4 * lg + q == lr) {
            sq[W * 16 + lr]       = acc[0][q];       // tile (W,W)
            sq[(7 - W) * 16 + lr] = acc[8 - W][q];   // tile (7-W,7-W)
        }
    }
}

// Borjesson-Sundberg Q(z) ~ phi(z)/((1-A)z + A*sqrt(z^2+B)); rel err <~0.5%.
// q_axb = F1 + F2 - 2 F1 F2 is relative-accurate (no cancellation).
__device__ __forceinline__ float entry_ll(float g, float sqn, float sqm,
        uint_t cw, float lam, float one_m2l) {
    const float d2 = fmaxf(sqn + sqm - 2.0f * g, 0.0f);
    const float pd = __builtin_amdgcn_sqrtf(d2);
    const float A = 0.344f, B = 5.334f, IA = 0.656f, C = 0.3989422804f;
    const float z1 = 0.70710678f * pd, z2 = 0.5f * pd;
    const float e1 = __expf(-0.25f  * d2) * C;   // phi(z1)
    const float e2 = __expf(-0.125f * d2) * C;   // phi(z2)
    const float den1 = fmaf(A, __builtin_amdgcn_sqrtf(fmaf(0.5f,  d2, B)), IA * z1);
    const float den2 = fmaf(A, __builtin_amdgcn_sqrtf(fmaf(0.25f, d2, B)), IA * z2);
    const float F1 = e1 * __builtin_amdgcn_rcpf(den1);
    const float F2 = e2 * __builtin_amdgcn_rcpf(den2);
    const float qax = F1 + F2 - 2.0f * F1 * F2;
    float qp = fmaf(one_m2l, qax, lam);
    qp = fminf(fmaxf(qp, 1e-7f), 1.0f - 1e-7f);
    const float pp = 1.0f - qp;
    const float c   = bf2f((ushort_t)(cw & 0xffffu));
    const float amc = bf2f((ushort_t)(cw >> 16));
    return c * __logf(pp) + amc * __logf(qp);
}

__device__ __forceinline__ float tile_ll(f4 a, int TR, int TC, bool diag,
        int lr, int lg, const float* sq, const uint_t* __restrict__ cnt,
        float lam, float one_m2l) {
    float s = 0.0f;
    #pragma unroll
    for (int q = 0; q < 4; ++q) {
        const int n = TR * 16 + 4 * lg + q;
        const int m = TC * 16 + lr;
        if (!diag || (4 * lg + q) <= lr)
            s += entry_ll(a[q], sq[n], sq[m], cnt[n * 128 + m], lam, one_m2l);
    }
    return s;
}

template<int W>
__device__ __forceinline__ float epi(const f4 (&acc)[9], const float* sq,
        const uint_t* __restrict__ cnt, int lr, int lg, float lam, float one_m2l) {
    constexpr int RA = W, RB = 7 - W;
    float s = 0.0f;
    #pragma unroll
    for (int TC = W; TC < 8; ++TC) {
        s += tile_ll(acc[TC - W], RA, TC, (TC == RA), lr, lg, sq, cnt, lam, one_m2l);
        if (TC >= RB)
            s += tile_ll(acc[TC + 1], RB, TC, (TC == RB), lr, lg, sq, cnt, lam, one_m2l);
    }
    return s;
}

__global__ __launch_bounds__(256, 4) void ll_kernel(
        const uint_t* __restrict__ x_g,
        const float* __restrict__ l_raw, const uint_t* __restrict__ cnt,
        float* __restrict__ sums, int s_base) {
    const int li = blockIdx.x;
    const int s  = s_base + li;
    const int t  = threadIdx.x;

    __shared__ __align__(16) ushort_t Xs[NNODES * 128];   // 32 KB
    __shared__ float sq[NNODES];
    __shared__ float wsum[4];

    const uint_t* gx = x_g + (size_t)li * NNODES * 64;
    const int l = t & 63, w = t >> 6, lr = l & 15, lg = l >> 4;

    // fill LDS (swizzled) with 16B chunks; 2048 chunks over 256 threads
    #pragma unroll
    for (int ii = 0; ii < 8; ++ii) {
        const int i = t + ii * 256;
        const int row = i >> 4, j = i & 15;
        const uint4 v = *(const uint4*)(gx + row * 64 + j * 4);
        const int b = ((row << 8) + (j << 4)) ^ ((row & 7) << 4);
        *(uint4*)((char*)Xs + b) = v;
    }
    __syncthreads();

    f4 acc[9];
    #pragma unroll
    for (int i = 0; i < 9; ++i) acc[i] = (f4)(0.0f);

    switch (w) {
        case 0: gram_w<0>(Xs, acc, lr, lg); write_sq<0>(acc, sq, lr, lg); break;
        case 1: gram_w<1>(Xs, acc, lr, lg); write_sq<1>(acc, sq, lr, lg); break;
        case 2: gram_w<2>(Xs, acc, lr, lg); write_sq<2>(acc, sq, lr, lg); break;
        default: gram_w<3>(Xs, acc, lr, lg); write_sq<3>(acc, sq, lr, lg); break;
    }
    __syncthreads();

    const float lam = 0.06f * normal_cdf_f(l_raw[s]);
    const float one_m2l = 1.0f - 2.0f * lam;
    float ll = 0.0f;
    switch (w) {
        case 0: ll = epi<0>(acc, sq, cnt, lr, lg, lam, one_m2l); break;
        case 1: ll = epi<1>(acc, sq, cnt, lr, lg, lam, one_m2l); break;
        case 2: ll = epi<2>(acc, sq, cnt, lr, lg, lam, one_m2l); break;
        default: ll = epi<3>(acc, sq, cnt, lr, lg, lam, one_m2l); break;
    }

    const float wtot = wave_sum(ll);
    if (l == 0) wsum[w] = wtot;
    __syncthreads();
    if (t == 0) sums[s] = wsum[0] + wsum[1] + wsum[2] + wsum[3];
}

// ---------------------------------------------------------------------------
// Kernel 3: deterministic mean over S
// ---------------------------------------------------------------------------
__global__ __launch_bounds__(256) void reduce_kernel(
        const float* __restrict__ sums, float* __restrict__ out) {
    __shared__ double sh[256];
    const int t = threadIdx.x;
    double acc = 0.0;
    for (int i = t; i < S_TOT; i += 256) acc += (double)sums[i];
    sh[t] = acc;
    __syncthreads();
    for (int off = 128; off > 0; off >>= 1) {
        if (t < off) sh[t] += sh[t + off];
        __syncthreads();
    }
    if (t == 0) out[0] = (float)(sh[0] / (double)S_TOT);
}

// ---------------------------------------------------------------------------
extern "C" void kernel_launch(void* const* d_in, const int* in_sizes, int n_in,
                              void* d_out, int out_size, void* d_ws, size_t ws_size,
                              hipStream_t stream) {
    (void)in_sizes; (void)n_in; (void)out_size;
    const float* d_raw = (const float*)d_in[0];
    const float* c_raw = (const float*)d_in[1];
    const float* a_raw = (const float*)d_in[2];
    const float* l_raw = (const float*)d_in[3];
    const int*   all_t = (const int*)d_in[4];
    const int*   cor_t = (const int*)d_in[5];
    float* out = (float*)d_out;

    char*   ws   = (char*)d_ws;
    float*  sums = (float*)ws;                        // 8 KB
    uint_t* cnt  = (uint_t*)(ws + 8192);              // 64 KB packed counts
    char*   xbase = ws + 8192 + 65536;
    const size_t per_sample = (size_t)NNODES * 64 * sizeof(uint_t);  // 32 KB

    const size_t head = 8192 + 65536;
    size_t avail = (ws_size > head) ? ws_size - head : 0;
    int chunk = (int)(avail / per_sample);
    if (chunk > S_TOT) chunk = S_TOT;
    if (chunk < 1) chunk = 1;

    prep_counts<<<64, 256, 0, stream>>>(all_t, cor_t, cnt);

    for (int s0 = 0; s0 < S_TOT; s0 += chunk) {
        const int nblk = (S_TOT - s0 < chunk) ? (S_TOT - s0) : chunk;
        uint_t* xbuf = (uint_t*)xbase;
        traj_kernel<<<nblk, 64, 0, stream>>>(d_raw, c_raw, a_raw, xbuf, s0);
        ll_kernel<<<nblk, 256, 0, stream>>>(xbuf, l_raw, cnt, sums, s0);
    }
    reduce_kernel<<<1, 256, 0, stream>>>(sums, out);
}